// Round 3
// baseline (95.463 us; speedup 1.0000x reference)
//
#include <hip/hip_runtime.h>
#include <math.h>

#define B 8
#define N 2048
#define NP1 2049
#define FIN 128
#define FOUT 64
#define NS 0.2f

typedef unsigned long long u64;

__device__ __forceinline__ unsigned f2u(float f) {
  unsigned u = __float_as_uint(f);
  return (u & 0x80000000u) ? ~u : (u | 0x80000000u);
}
__device__ __forceinline__ float u2f(unsigned v) {
  unsigned u = (v & 0x80000000u) ? (v ^ 0x80000000u) : ~v;
  return __uint_as_float(u);
}

// ---------------------------------------------------------------------------
// K1: per row: h = x@W, s1 = h.a1, s2 = h.a2, u/uq/e2/eq2 = exps
// block = 256 = 4 rows x 64 lanes (one wave per row)
// ---------------------------------------------------------------------------
__global__ void k_hs(const float* __restrict__ x, const float* __restrict__ W,
                     const float* __restrict__ a, float* __restrict__ h,
                     float* __restrict__ s1, float* __restrict__ s2,
                     float* __restrict__ u, float* __restrict__ uq,
                     float* __restrict__ e2, float* __restrict__ eq2) {
  __shared__ float xs[4 * FIN];
  const int row0 = blockIdx.x * 4;
  const int lane = threadIdx.x & 63;
  const int r = threadIdx.x >> 6;

  if (threadIdx.x < 128) {
    const float4* src = (const float4*)(x + (size_t)row0 * FIN);
    ((float4*)xs)[threadIdx.x] = src[threadIdx.x];
  }
  __syncthreads();

  float acc = 0.f;
#pragma unroll 8
  for (int k = 0; k < FIN; ++k)
    acc = fmaf(xs[r * FIN + k], W[k * FOUT + lane], acc);

  const int row = row0 + r;
  h[(size_t)row * FOUT + lane] = acc;

  float v1 = acc * a[lane];
  float v2 = acc * a[FOUT + lane];
#pragma unroll
  for (int off = 32; off > 0; off >>= 1) {
    v1 += __shfl_xor(v1, off, 64);
    v2 += __shfl_xor(v2, off, 64);
  }
  if (lane == 0) {
    s1[row] = v1;
    s2[row] = v2;
    u[row] = expf(v1);
    uq[row] = expf(NS * v1);
    e2[row] = expf(v2);
    eq2[row] = expf(NS * v2);
  }
}

// ---------------------------------------------------------------------------
// K2: per (b,j): Z_j = e2_j * sum_{i: cond} u_i + eq2_j * sum_{!cond} uq_i
//     cond <=> u_i * e2_j >= 1  (== s1_i + s2_j >= 0; boundary continuous)
//     A_j = e2_j / Z_j,  Bc_j = eq2_j / Z_j
// block = 256 = 64 j x 4 i-chunks of 512; grid = B * (N/64)
// ---------------------------------------------------------------------------
__global__ void k_z(const float* __restrict__ u, const float* __restrict__ uq,
                    const float* __restrict__ e2, const float* __restrict__ eq2,
                    float* __restrict__ A, float* __restrict__ Bc) {
  __shared__ float us[N], uqs[N];
  __shared__ float rsu[4][64], rsq[4][64];
  const int b = blockIdx.x / (N / 64);
  const int j0 = (blockIdx.x % (N / 64)) * 64;
  const int jl = threadIdx.x & 63;
  const int ic = threadIdx.x >> 6;

  for (int t = threadIdx.x; t < N; t += 256) {
    us[t] = u[b * N + t];
    uqs[t] = uq[b * N + t];
  }
  __syncthreads();

  const float E = e2[b * N + j0 + jl];
  float su = 0.f, sq = 0.f;
  const int ibeg = ic * (N / 4), iend = ibeg + (N / 4);
#pragma unroll 4
  for (int i = ibeg; i < iend; ++i) {
    float ui = us[i];
    bool cond = (ui * E >= 1.0f);
    su += cond ? ui : 0.f;
    sq += cond ? 0.f : uqs[i];
  }
  rsu[ic][jl] = su;
  rsq[ic][jl] = sq;
  __syncthreads();

  if (threadIdx.x < 64) {
    int j = j0 + threadIdx.x;
    float SU = rsu[0][threadIdx.x] + rsu[1][threadIdx.x] +
               rsu[2][threadIdx.x] + rsu[3][threadIdx.x];
    float SQ = rsq[0][threadIdx.x] + rsq[1][threadIdx.x] +
               rsq[2][threadIdx.x] + rsq[3][threadIdx.x];
    float Ej = e2[b * N + j];
    float Eq = eq2[b * N + j];
    float Z = Ej * SU + Eq * SQ;
    A[b * N + j] = Ej / Z;
    Bc[b * N + j] = Eq / Z;
  }
}

// ---------------------------------------------------------------------------
// K2b: brute-force rank of each s2 among its batch (u64 key|idx, tie-free),
//      then scatter -> s2s (sorted keys), idx2 (permutation).
// block = 256 = 64 elements x 4 count-chunks of 512; grid = B * (N/64)
// ---------------------------------------------------------------------------
__global__ void k_rank(const float* __restrict__ s2, float* __restrict__ s2s,
                       int* __restrict__ idx2) {
  __shared__ u64 keys[N];        // 16 KB
  __shared__ int rcnt[4][64];
  const int b = blockIdx.x / (N / 64);
  const int base = (blockIdx.x % (N / 64)) * 64;
  const int jl = threadIdx.x & 63;
  const int ic = threadIdx.x >> 6;

  for (int t = threadIdx.x; t < N; t += 256)
    keys[t] = ((u64)f2u(s2[b * N + t]) << 32) | (unsigned)t;
  __syncthreads();

  const u64 mykey = keys[base + jl];
  int cnt = 0;
  const int ibeg = ic * (N / 4), iend = ibeg + (N / 4);
#pragma unroll 8
  for (int i = ibeg; i < iend; ++i)
    cnt += (keys[i] < mykey) ? 1 : 0;
  rcnt[ic][jl] = cnt;
  __syncthreads();

  if (threadIdx.x < 64) {
    const int e = base + threadIdx.x;
    const int rank = rcnt[0][threadIdx.x] + rcnt[1][threadIdx.x] +
                     rcnt[2][threadIdx.x] + rcnt[3][threadIdx.x];
    const u64 kv = keys[e];
    s2s[b * N + rank] = u2f((unsigned)(kv >> 32));
    idx2[b * N + rank] = e;
  }
}

// ---------------------------------------------------------------------------
// K3a: chunk totals of A*h and B*h in s2-sorted order (32-row chunks)
// grid = B*64 blocks of 64 threads (lane = f)
// ---------------------------------------------------------------------------
#define NCH 64
#define CHS 32
__global__ void k_scan1(const float* __restrict__ A, const float* __restrict__ Bc,
                        const float* __restrict__ h, const int* __restrict__ idx2,
                        float* __restrict__ ctA, float* __restrict__ ctB) {
  const int b = blockIdx.x >> 6, w = blockIdx.x & 63;
  const int f = threadIdx.x;
  float ta = 0.f, tb = 0.f;
  for (int rr = 0; rr < CHS; ++rr) {
    const int r = w * CHS + rr;
    const int j = idx2[b * N + r];
    const float hv = h[((size_t)b * N + j) * FOUT + f];
    ta = fmaf(A[b * N + j], hv, ta);
    tb = fmaf(Bc[b * N + j], hv, tb);
  }
  ctA[(b * NCH + w) * FOUT + f] = ta;
  ctB[(b * NCH + w) * FOUT + f] = tb;
}

// ---------------------------------------------------------------------------
// K3b: finalize vector scans: PB[c][f] = prefix of B*h (ranks < c),
//      SA[c][f] = suffix of A*h (ranks >= c).  grid = B*64 x 64
// ---------------------------------------------------------------------------
__global__ void k_scan2(const float* __restrict__ A, const float* __restrict__ Bc,
                        const float* __restrict__ h, const int* __restrict__ idx2,
                        const float* __restrict__ ctA, const float* __restrict__ ctB,
                        float* __restrict__ SA, float* __restrict__ PB) {
  const int b = blockIdx.x >> 6, w = blockIdx.x & 63;
  const int f = threadIdx.x;
  float offA = 0.f, offB = 0.f;
  for (int w2 = 0; w2 < NCH; ++w2) {
    const float ta = ctA[(b * NCH + w2) * FOUT + f];
    const float tb = ctB[(b * NCH + w2) * FOUT + f];
    if (w2 > w) offA += ta;
    if (w2 < w) offB += tb;
  }
  float run = offB;
  for (int rr = 0; rr < CHS; ++rr) {
    const int r = w * CHS + rr;
    const int j = idx2[b * N + r];
    const float hv = h[((size_t)b * N + j) * FOUT + f];
    run = fmaf(Bc[b * N + j], hv, run);
    PB[((size_t)b * NP1 + r + 1) * FOUT + f] = run;
  }
  run = offA;
  for (int rr = CHS - 1; rr >= 0; --rr) {
    const int r = w * CHS + rr;
    const int j = idx2[b * N + r];
    const float hv = h[((size_t)b * N + j) * FOUT + f];
    run = fmaf(A[b * N + j], hv, run);
    SA[((size_t)b * NP1 + r) * FOUT + f] = run;
  }
  if (w == 0) {
    PB[((size_t)b * NP1 + 0) * FOUT + f] = 0.f;
    SA[((size_t)b * NP1 + N) * FOUT + f] = 0.f;
  }
}

// ---------------------------------------------------------------------------
// K4: per row i: wave-ballot lower_bound(s2s, -s1_i) -> c;
//     out[f] = lrelu(u_i*SA[c][f] + uq_i*PB[c][f])
// grid = B*N/4 blocks of 256 (4 waves, one row per wave)
// ---------------------------------------------------------------------------
__global__ void k_out(const float* __restrict__ s1, const float* __restrict__ u,
                      const float* __restrict__ uq, const float* __restrict__ s2s,
                      const float* __restrict__ SA, const float* __restrict__ PB,
                      float* __restrict__ out) {
  const int wv = threadIdx.x >> 6;
  const int lane = threadIdx.x & 63;
  const int row = blockIdx.x * 4 + wv;
  const int b = row >> 11;
  const float t = -s1[row];
  const float* ks = s2s + b * N;

  const float v0 = ks[lane * 32];
  const unsigned long long m = __ballot(v0 < t);
  const int m1 = __popcll(m);
  int c;
  if (m1 == 0) {
    c = 0;
  } else {
    const int base = (m1 - 1) * 32;
    const float v1 = ks[base + (lane & 31)];
    const unsigned long long m2 = __ballot((lane < 32) && (v1 < t));
    c = base + __popcll(m2);
  }
  const float sa = SA[((size_t)b * NP1 + c) * FOUT + lane];
  const float pb = PB[((size_t)b * NP1 + c) * FOUT + lane];
  const float v = u[row] * sa + uq[row] * pb;
  out[(size_t)row * FOUT + lane] = v >= 0.f ? v : NS * v;
}

extern "C" void kernel_launch(void* const* d_in, const int* in_sizes, int n_in,
                              void* d_out, int out_size, void* d_ws, size_t ws_size,
                              hipStream_t stream) {
  const float* x = (const float*)d_in[0];   // (8,2048,128)
  const float* W = (const float*)d_in[1];   // (128,64)
  const float* a = (const float*)d_in[2];   // (128,1)
  float* out = (float*)d_out;               // (8,2048,64)

  // h lives in d_out as scratch; consumed by k_scan1/k_scan2 before k_out
  // overwrites d_out with the final result.
  float* h = out;

  float* ws = (float*)d_ws;
  float* s1 = ws;                 // B*N each
  float* s2 = s1 + B * N;
  float* u = s2 + B * N;
  float* uq = u + B * N;
  float* e2 = uq + B * N;
  float* eq2 = e2 + B * N;
  float* A = eq2 + B * N;
  float* Bc = A + B * N;
  float* s2s = Bc + B * N;
  int* idx2 = (int*)(s2s + B * N);
  float* ctA = (float*)(idx2 + B * N);  // B*64*64
  float* ctB = ctA + B * NCH * FOUT;
  float* SA = ctB + B * NCH * FOUT;     // B*(N+1)*64
  float* PB = SA + (size_t)B * NP1 * FOUT;

  k_hs<<<B * N / 4, 256, 0, stream>>>(x, W, a, h, s1, s2, u, uq, e2, eq2);
  k_z<<<B * (N / 64), 256, 0, stream>>>(u, uq, e2, eq2, A, Bc);
  k_rank<<<B * (N / 64), 256, 0, stream>>>(s2, s2s, idx2);
  k_scan1<<<B * NCH, FOUT, 0, stream>>>(A, Bc, h, idx2, ctA, ctB);
  k_scan2<<<B * NCH, FOUT, 0, stream>>>(A, Bc, h, idx2, ctA, ctB, SA, PB);
  k_out<<<B * N / 4, 256, 0, stream>>>(s1, u, uq, s2s, SA, PB, out);
}